// Round 1
// baseline (503.939 us; speedup 1.0000x reference)
//
#include <hip/hip_runtime.h>
#include <hip/hip_bf16.h>
#include <math.h>

typedef __bf16 bfx8 __attribute__((ext_vector_type(8)));
typedef float f32x4 __attribute__((ext_vector_type(4)));

#define NELEM_W 36864
#define CHW     50176   // 224*224

// ---------- mask dtype detection (bool may arrive as u8 / i32 / f32 / bf16) ----------
// Probes only the first 4096 bytes (safe under every candidate storage width).
__device__ __forceinline__ int detect_mask_kind(const void* mask, int tid, int nthreads,
                                                int* s_flags, int* s_kind) {
  if (tid < 8) s_flags[tid] = 0;
  __syncthreads();
  const unsigned int* mw = (const unsigned int*)mask;
  int lowbf = 0, notf32 = 0, anyf32 = 0, noti32 = 0, anyi1 = 0;
  for (int i = tid; i < 1024; i += nthreads) {
    unsigned v = mw[i];
    if ((v & 0xFFFFu) == 0x3F80u) lowbf = 1;          // bf16 1.0 in low half
    if (!(v == 0u || v == 0x3F800000u)) notf32 = 1;
    if (v == 0x3F800000u) anyf32 = 1;
    if (!(v == 0u || v == 1u)) noti32 = 1;
    if (v == 1u) anyi1 = 1;
  }
  if (lowbf)  atomicOr(&s_flags[0], 1);
  if (notf32) atomicOr(&s_flags[1], 1);
  if (anyf32) atomicOr(&s_flags[2], 1);
  if (noti32) atomicOr(&s_flags[3], 1);
  if (anyi1)  atomicOr(&s_flags[4], 1);
  __syncthreads();
  if (tid == 0) {
    int kind;
    if (s_flags[0]) kind = 3;                      // bf16 0/1
    else if (!s_flags[1] && s_flags[2]) kind = 2;  // f32 0/1
    else if (!s_flags[3] && s_flags[4]) kind = 1;  // i32 0/1
    else kind = 0;                                 // u8 bool
    *s_kind = kind;
  }
  __syncthreads();
  return *s_kind;
}

__device__ __forceinline__ bool mask_val(const void* mask, int kind, int e) {
  switch (kind) {
    case 1:  return ((const int*)mask)[e] != 0;
    case 2:  return ((const float*)mask)[e] != 0.0f;
    case 3:  return ((const unsigned short*)mask)[e] != 0;
    default: return ((const unsigned char*)mask)[e] != 0;
  }
}

// ---------- k1: deterministic masked stats, per-block partials ----------
__global__ __launch_bounds__(512) void stats_kernel(const float* __restrict__ W,
                                                    const void* __restrict__ mask,
                                                    float* __restrict__ ws_part) {
  __shared__ int s_flags[8]; __shared__ int s_kind;
  __shared__ float s_red[3][8];
  const int tid = threadIdx.x;
  int kind = detect_mask_kind(mask, tid, 512, s_flags, &s_kind);
  int e = blockIdx.x * 512 + tid;
  float w = W[e];
  bool m = mask_val(mask, kind, e);
  float s1 = m ? fabsf(w) : 0.f;
  float s2 = m ? w * w   : 0.f;
  float c  = m ? 1.f     : 0.f;
  #pragma unroll
  for (int o = 32; o > 0; o >>= 1) {
    s1 += __shfl_down(s1, o); s2 += __shfl_down(s2, o); c += __shfl_down(c, o);
  }
  int wv = tid >> 6;
  if ((tid & 63) == 0) { s_red[0][wv] = s1; s_red[1][wv] = s2; s_red[2][wv] = c; }
  __syncthreads();
  if (tid == 0) {
    float a = 0, b = 0, cc = 0;
    for (int i = 0; i < 8; i++) { a += s_red[0][i]; b += s_red[1][i]; cc += s_red[2][i]; }
    ws_part[blockIdx.x * 4 + 0] = a;
    ws_part[blockIdx.x * 4 + 1] = b;
    ws_part[blockIdx.x * 4 + 2] = cc;
  }
}

// ---------- k2: finalize scale + quantize weights into Bq[kykx][oc][ic] (bf16 integer q) ----------
__global__ __launch_bounds__(512) void quant_kernel(const float* __restrict__ W,
                                                    const void* __restrict__ mask,
                                                    const float* __restrict__ ws_part,
                                                    float* __restrict__ ws_scale,
                                                    unsigned short* __restrict__ Bq) {
  __shared__ int s_flags[8]; __shared__ int s_kind;
  __shared__ float s_scale;
  const int tid = threadIdx.x;
  int kind = detect_mask_kind(mask, tid, 512, s_flags, &s_kind);
  if (tid == 0) {
    float a = 0, b = 0, cc = 0;
    for (int i = 0; i < 72; i++) { a += ws_part[i*4]; b += ws_part[i*4+1]; cc += ws_part[i*4+2]; }
    float n  = fmaxf(cc, 1.f);
    float m1 = a / n, m2 = b / n;
    float alpha = 12.68f * sqrtf(m2) - 12.80f * m1;
    float scale = alpha / 127.0f;
    s_scale = scale;
    if (blockIdx.x == 0) ws_scale[0] = scale;
  }
  __syncthreads();
  float scale = s_scale;
  int e = blockIdx.x * 512 + tid;
  float w = W[e];
  float q = 0.f;
  if (mask_val(mask, kind, e)) {
    float v = w / scale;
    v = fminf(fmaxf(v, -127.f), 127.f);
    q = rintf(v);                                  // round half-to-even == jnp.round
  }
  // e = ((oc*64 + ic)*3 + ky)*3 + kx   ->  Bq[(ky*3+kx)][oc][ic]
  int kxy = e % 9; int t = e / 9; int ic = t & 63; int oc = t >> 6;
  __bf16 qb = (__bf16)q;                           // |q|<=127 -> exact in bf16
  Bq[(kxy * 64 + oc) * 64 + ic] = *(unsigned short*)&qb;
}

// ---------- conv: implicit GEMM, D[oc][m], 16x16x32 bf16 MFMA ----------
template<int NMF>
__device__ __forceinline__ void mfma_compute(const unsigned char* __restrict__ smem,
    const unsigned short* __restrict__ Bq, const float* __restrict__ ws_scale,
    const float* __restrict__ bias, float* __restrict__ out,
    int b, int y0, int x0, int wrow, int oc0, int mf0, int l15, int lg)
{
  f32x4 acc[NMF][2];
  #pragma unroll
  for (int m = 0; m < NMF; m++) { acc[m][0] = {0.f,0.f,0.f,0.f}; acc[m][1] = {0.f,0.f,0.f,0.f}; }

  #pragma unroll
  for (int ky = 0; ky < 3; ky++) {
    const int lrow = wrow + ky;
    #pragma unroll
    for (int kx = 0; kx < 3; kx++) {
      #pragma unroll
      for (int icb = 0; icb < 2; icb++) {
        const int ick = icb * 32 + lg * 8;
        // A operand: q[oc][ic] — lane row = oc (l&15), 8 contiguous ic
        const unsigned short* wp = Bq + (((ky*3 + kx) * 64 + oc0 + l15) * 64 + ick);
        bfx8 wf0 = *(const bfx8*)wp;
        bfx8 wf1 = *(const bfx8*)(wp + 16 * 64);   // oc0+16 block
        #pragma unroll
        for (int m = 0; m < NMF; m++) {
          int colw = kx + (mf0 + m) * 16 + l15;
          int off  = ((lrow * 114 + colw) * 128 + ick * 2) ^ ((colw & 7) << 4);
          bfx8 xf  = *(const bfx8*)(smem + off);   // B operand: x[ic][m]
          acc[m][0] = __builtin_amdgcn_mfma_f32_16x16x32_bf16(wf0, xf, acc[m][0], 0, 0, 0);
          acc[m][1] = __builtin_amdgcn_mfma_f32_16x16x32_bf16(wf1, xf, acc[m][1], 0, 0, 0);
        }
      }
    }
  }
  const float scale = ws_scale[0];
  const int yr = y0 + wrow;
  #pragma unroll
  for (int m = 0; m < NMF; m++) {
    #pragma unroll
    for (int n = 0; n < 2; n++) {
      #pragma unroll
      for (int r = 0; r < 4; r++) {
        int oc = oc0 + n * 16 + lg * 4 + r;        // D row = (lane>>4)*4 + reg
        float* op = out + (((size_t)(b * 64 + oc)) * 224 + yr) * 224 + x0 + (mf0 + m) * 16 + l15;
        *op = acc[m][n][r] * scale + bias[oc];
      }
    }
  }
}

__global__ __launch_bounds__(512, 4) void conv_kernel(const float* __restrict__ x,
    const unsigned short* __restrict__ Bq, const float* __restrict__ ws_scale,
    const float* __restrict__ bias, float* __restrict__ out)
{
  __shared__ __align__(16) unsigned char smem[4 * 114 * 128];  // 58368 B: [row][col][ic] bf16, XOR-swizzled
  const int tid = threadIdx.x;
  const int x0 = blockIdx.x * 112;
  const int y0 = blockIdx.y * 2;
  const int b  = blockIdx.z;

  // Stage rows y0-1..y0+2, cols x0-1..x0+112, all 64 ic; f32 -> bf16; zeros at pad.
  for (int e = tid; e < 4 * 8 * 114; e += 512) {
    int col = e % 114; int t = e / 114; int icg = t & 7; int row = t >> 3;
    int grow = y0 - 1 + row, gcol = x0 - 1 + col;
    bfx8 v;
    if ((unsigned)grow < 224u && (unsigned)gcol < 224u) {
      const float* src = x + (((size_t)(b * 64 + icg * 8)) * 224 + grow) * 224 + gcol;
      #pragma unroll
      for (int j = 0; j < 8; j++) v[j] = (__bf16)src[j * CHW];   // coalesced across lanes (col)
    } else {
      #pragma unroll
      for (int j = 0; j < 8; j++) v[j] = (__bf16)0.f;
    }
    int off = ((row * 114 + col) * 128 + icg * 16) ^ ((col & 7) << 4);
    *(bfx8*)(smem + off) = v;
  }
  __syncthreads();

  const int w = tid >> 6, lane = tid & 63;
  const int l15 = lane & 15, lg = lane >> 4;
  const int wrow = w >> 2;          // which of 2 output rows
  const int woc  = (w >> 1) & 1;    // oc half (0..31 / 32..63)
  const int wmf  = w & 1;           // mf half (mf 0..3 / 4..6)
  const int oc0  = woc * 32;
  if (wmf == 0) mfma_compute<4>(smem, Bq, ws_scale, bias, out, b, y0, x0, wrow, oc0, 0, l15, lg);
  else          mfma_compute<3>(smem, Bq, ws_scale, bias, out, b, y0, x0, wrow, oc0, 4, l15, lg);
}

extern "C" void kernel_launch(void* const* d_in, const int* in_sizes, int n_in,
                              void* d_out, int out_size, void* d_ws, size_t ws_size,
                              hipStream_t stream) {
  const float* x    = (const float*)d_in[0];
  const float* W    = (const float*)d_in[1];
  const void*  mask = d_in[2];
  const float* bias = (const float*)d_in[3];
  float* out = (float*)d_out;

  float*          ws_part  = (float*)d_ws;                         // 72*4 f32 partials
  float*          ws_scale = (float*)((char*)d_ws + 2048);         // 1 f32
  unsigned short* Bq       = (unsigned short*)((char*)d_ws + 4096);// 9*64*64 bf16 = 73728 B

  stats_kernel<<<72, 512, 0, stream>>>(W, mask, ws_part);
  quant_kernel<<<72, 512, 0, stream>>>(W, mask, ws_part, ws_scale, Bq);
  dim3 grid(2, 112, 16);   // (x-segment, y-tile of 2 rows, batch)
  conv_kernel<<<grid, 512, 0, stream>>>(x, Bq, ws_scale, bias, out);
}

// Round 2
// 475.942 us; speedup vs baseline: 1.0588x; 1.0588x over previous
//
#include <hip/hip_runtime.h>
#include <hip/hip_bf16.h>
#include <math.h>

typedef __bf16 bfx8 __attribute__((ext_vector_type(8)));
typedef float f32x4 __attribute__((ext_vector_type(4)));

#define NELEM_W 36864
#define CHW     50176   // 224*224

// ---------- mask dtype detection (bool may arrive as u8 / i32 / f32 / bf16) ----------
__device__ __forceinline__ int detect_mask_kind(const void* mask, int tid, int nthreads,
                                                int* s_flags, int* s_kind) {
  if (tid < 8) s_flags[tid] = 0;
  __syncthreads();
  const unsigned int* mw = (const unsigned int*)mask;
  int lowbf = 0, notf32 = 0, anyf32 = 0, noti32 = 0, anyi1 = 0;
  for (int i = tid; i < 1024; i += nthreads) {
    unsigned v = mw[i];
    if ((v & 0xFFFFu) == 0x3F80u) lowbf = 1;
    if (!(v == 0u || v == 0x3F800000u)) notf32 = 1;
    if (v == 0x3F800000u) anyf32 = 1;
    if (!(v == 0u || v == 1u)) noti32 = 1;
    if (v == 1u) anyi1 = 1;
  }
  if (lowbf)  atomicOr(&s_flags[0], 1);
  if (notf32) atomicOr(&s_flags[1], 1);
  if (anyf32) atomicOr(&s_flags[2], 1);
  if (noti32) atomicOr(&s_flags[3], 1);
  if (anyi1)  atomicOr(&s_flags[4], 1);
  __syncthreads();
  if (tid == 0) {
    int kind;
    if (s_flags[0]) kind = 3;
    else if (!s_flags[1] && s_flags[2]) kind = 2;
    else if (!s_flags[3] && s_flags[4]) kind = 1;
    else kind = 0;
    *s_kind = kind;
  }
  __syncthreads();
  return *s_kind;
}

__device__ __forceinline__ bool mask_val(const void* mask, int kind, int e) {
  switch (kind) {
    case 1:  return ((const int*)mask)[e] != 0;
    case 2:  return ((const float*)mask)[e] != 0.0f;
    case 3:  return ((const unsigned short*)mask)[e] != 0;
    default: return ((const unsigned char*)mask)[e] != 0;
  }
}

// ---------- k1: deterministic masked stats, per-block partials ----------
__global__ __launch_bounds__(512) void stats_kernel(const float* __restrict__ W,
                                                    const void* __restrict__ mask,
                                                    float* __restrict__ ws_part) {
  __shared__ int s_flags[8]; __shared__ int s_kind;
  __shared__ float s_red[3][8];
  const int tid = threadIdx.x;
  int kind = detect_mask_kind(mask, tid, 512, s_flags, &s_kind);
  int e = blockIdx.x * 512 + tid;
  float w = W[e];
  bool m = mask_val(mask, kind, e);
  float s1 = m ? fabsf(w) : 0.f;
  float s2 = m ? w * w   : 0.f;
  float c  = m ? 1.f     : 0.f;
  #pragma unroll
  for (int o = 32; o > 0; o >>= 1) {
    s1 += __shfl_down(s1, o); s2 += __shfl_down(s2, o); c += __shfl_down(c, o);
  }
  int wv = tid >> 6;
  if ((tid & 63) == 0) { s_red[0][wv] = s1; s_red[1][wv] = s2; s_red[2][wv] = c; }
  __syncthreads();
  if (tid == 0) {
    float a = 0, b = 0, cc = 0;
    for (int i = 0; i < 8; i++) { a += s_red[0][i]; b += s_red[1][i]; cc += s_red[2][i]; }
    ws_part[blockIdx.x * 4 + 0] = a;
    ws_part[blockIdx.x * 4 + 1] = b;
    ws_part[blockIdx.x * 4 + 2] = cc;
  }
}

// ---------- k2: finalize scale + quantize weights into Bq[kykx][oc][ic] ----------
__global__ __launch_bounds__(512) void quant_kernel(const float* __restrict__ W,
                                                    const void* __restrict__ mask,
                                                    const float* __restrict__ ws_part,
                                                    float* __restrict__ ws_scale,
                                                    unsigned short* __restrict__ Bq) {
  __shared__ int s_flags[8]; __shared__ int s_kind;
  __shared__ float s_scale;
  const int tid = threadIdx.x;
  int kind = detect_mask_kind(mask, tid, 512, s_flags, &s_kind);
  if (tid == 0) {
    float a = 0, b = 0, cc = 0;
    for (int i = 0; i < 72; i++) { a += ws_part[i*4]; b += ws_part[i*4+1]; cc += ws_part[i*4+2]; }
    float n  = fmaxf(cc, 1.f);
    float m1 = a / n, m2 = b / n;
    float alpha = 12.68f * sqrtf(m2) - 12.80f * m1;
    float scale = alpha / 127.0f;
    s_scale = scale;
    if (blockIdx.x == 0) ws_scale[0] = scale;
  }
  __syncthreads();
  float scale = s_scale;
  int e = blockIdx.x * 512 + tid;
  float w = W[e];
  float q = 0.f;
  if (mask_val(mask, kind, e)) {
    float v = w / scale;
    v = fminf(fmaxf(v, -127.f), 127.f);
    q = rintf(v);
  }
  int kxy = e % 9; int t = e / 9; int ic = t & 63; int oc = t >> 6;
  __bf16 qb = (__bf16)q;
  Bq[(kxy * 64 + oc) * 64 + ic] = *(unsigned short*)&qb;
}

// ---------- conv: implicit GEMM, 4 rows x 64 cols tile, 3 blocks/CU ----------
// LDS = 6 rows x 66 cols x 64ic bf16 = 50688 B -> 3 blocks/CU, 24 waves/CU.
// 8 waves = 4 rows x 2 oc-halves; each wave: 1 row x 32 oc x 64 x (NMF=4).
__global__ __launch_bounds__(512, 6) void conv_kernel(const float* __restrict__ x,
    const unsigned short* __restrict__ Bq, const float* __restrict__ ws_scale,
    const float* __restrict__ bias, float* __restrict__ out)
{
  __shared__ __align__(16) unsigned char smem[6 * 66 * 128];  // 50688 B
  const int tid = threadIdx.x;

  // T1: bijective chunked XCD swizzle (3584 blocks, 3584 % 8 == 0).
  // HW round-robins consecutive ids across 8 XCDs; remap so each XCD owns a
  // y-contiguous logical chunk -> y-halo lines hit the same XCD's L2.
  int lin = blockIdx.x + (int)(gridDim.x * (blockIdx.y + gridDim.y * blockIdx.z));
  int logical = (lin & 7) * 448 + (lin >> 3);
  const int bx = logical & 3;          // x-segment (0..3), 64 wide (last padded)
  int rr = logical >> 2;
  const int by = rr % 56;              // y-tile of 4 rows
  const int b  = rr / 56;              // batch
  const int x0 = bx * 64;
  const int y0 = by * 4;

  // Stage rows y0-1..y0+4, cols x0-1..x0+64, all 64 ic; f32 -> bf16; zero pad.
  for (int e = tid; e < 6 * 8 * 66; e += 512) {
    int col = e % 66; int t = e / 66; int icg = t & 7; int row = t >> 3;
    int grow = y0 - 1 + row, gcol = x0 - 1 + col;
    bfx8 v;
    if ((unsigned)grow < 224u && (unsigned)gcol < 224u) {
      const float* src = x + (((size_t)(b * 64 + icg * 8)) * 224 + grow) * 224 + gcol;
      #pragma unroll
      for (int j = 0; j < 8; j++) v[j] = (__bf16)src[j * CHW];
    } else {
      #pragma unroll
      for (int j = 0; j < 8; j++) v[j] = (__bf16)0.f;
    }
    int off = ((row * 66 + col) * 128 + icg * 16) ^ ((col & 7) << 4);
    *(bfx8*)(smem + off) = v;
  }
  __syncthreads();

  const int w = tid >> 6, lane = tid & 63;
  const int l15 = lane & 15, lg = lane >> 4;
  const int wrow = w >> 1;             // output row within tile (0..3)
  const int oc0  = (w & 1) * 32;       // oc half

  f32x4 acc[4][2];
  #pragma unroll
  for (int m = 0; m < 4; m++) { acc[m][0] = {0.f,0.f,0.f,0.f}; acc[m][1] = {0.f,0.f,0.f,0.f}; }

  #pragma unroll
  for (int ky = 0; ky < 3; ky++) {
    const int lrow = wrow + ky;
    #pragma unroll
    for (int kx = 0; kx < 3; kx++) {
      #pragma unroll
      for (int icb = 0; icb < 2; icb++) {
        const int ick = icb * 32 + lg * 8;
        const unsigned short* wp = Bq + (((ky*3 + kx) * 64 + oc0 + l15) * 64 + ick);
        bfx8 wf0 = *(const bfx8*)wp;
        bfx8 wf1 = *(const bfx8*)(wp + 16 * 64);
        #pragma unroll
        for (int m = 0; m < 4; m++) {
          int colw = kx + m * 16 + l15;
          int off  = ((lrow * 66 + colw) * 128 + ick * 2) ^ ((colw & 7) << 4);
          bfx8 xf  = *(const bfx8*)(smem + off);
          acc[m][0] = __builtin_amdgcn_mfma_f32_16x16x32_bf16(wf0, xf, acc[m][0], 0, 0, 0);
          acc[m][1] = __builtin_amdgcn_mfma_f32_16x16x32_bf16(wf1, xf, acc[m][1], 0, 0, 0);
        }
      }
    }
  }

  const float scale = ws_scale[0];
  const int yr = y0 + wrow;
  #pragma unroll
  for (int m = 0; m < 4; m++) {
    const int gcol = x0 + m * 16 + l15;
    if (gcol < 224) {
      #pragma unroll
      for (int n = 0; n < 2; n++) {
        #pragma unroll
        for (int r = 0; r < 4; r++) {
          int oc = oc0 + n * 16 + lg * 4 + r;
          out[(((size_t)(b * 64 + oc)) * 224 + yr) * 224 + gcol] = acc[m][n][r] * scale + bias[oc];
        }
      }
    }
  }
}

extern "C" void kernel_launch(void* const* d_in, const int* in_sizes, int n_in,
                              void* d_out, int out_size, void* d_ws, size_t ws_size,
                              hipStream_t stream) {
  const float* x    = (const float*)d_in[0];
  const float* W    = (const float*)d_in[1];
  const void*  mask = d_in[2];
  const float* bias = (const float*)d_in[3];
  float* out = (float*)d_out;

  float*          ws_part  = (float*)d_ws;
  float*          ws_scale = (float*)((char*)d_ws + 2048);
  unsigned short* Bq       = (unsigned short*)((char*)d_ws + 4096);

  stats_kernel<<<72, 512, 0, stream>>>(W, mask, ws_part);
  quant_kernel<<<72, 512, 0, stream>>>(W, mask, ws_part, ws_scale, Bq);
  dim3 grid(4, 56, 16);   // (x-segment of 64, y-tile of 4 rows, batch) = 3584 blocks
  conv_kernel<<<grid, 512, 0, stream>>>(x, Bq, ws_scale, bias, out);
}